// Round 5
// baseline (612.007 us; speedup 1.0000x reference)
//
#include <hip/hip_runtime.h>
#include <cstdint>
#include <cstddef>

typedef __bf16          bf16x8  __attribute__((ext_vector_type(8)));
typedef float           f32x4   __attribute__((ext_vector_type(4)));
typedef unsigned short  u16x8   __attribute__((ext_vector_type(8)));

__device__ __forceinline__ unsigned short f32_bf16_rne(float f) {
  union { float f; unsigned u; } v; v.f = f;
  unsigned u = v.u + 0x7FFFu + ((v.u >> 16) & 1u);
  return (unsigned short)(u >> 16);
}

// ---------------- flat fp32 -> bf16 convert (vectorized, G13) ----------------
__global__ void cvt_f32_bf16(const float* __restrict__ in,
                             unsigned short* __restrict__ out, int n8) {
  int idx = blockIdx.x * 256 + threadIdx.x;
  int stride = gridDim.x * 256;
  for (int i = idx; i < n8; i += stride) {
    float4 a = ((const float4*)in)[2 * (size_t)i];
    float4 b = ((const float4*)in)[2 * (size_t)i + 1];
    u16x8 o;
    o[0] = f32_bf16_rne(a.x); o[1] = f32_bf16_rne(a.y);
    o[2] = f32_bf16_rne(a.z); o[3] = f32_bf16_rne(a.w);
    o[4] = f32_bf16_rne(b.x); o[5] = f32_bf16_rne(b.y);
    o[6] = f32_bf16_rne(b.z); o[7] = f32_bf16_rne(b.w);
    *(u16x8*)(out + (size_t)i * 8) = o;
  }
}

// ------------- beta (H x O, f32) -> betaT (O x H, bf16) transpose ------------
__global__ void cvt_transpose(const float* __restrict__ in,
                              unsigned short* __restrict__ out, int H, int O) {
  __shared__ float tile[32][33];
  int o0 = blockIdx.x * 32, h0 = blockIdx.y * 32;
  int tx = threadIdx.x & 31, ty = threadIdx.x >> 5;
  #pragma unroll
  for (int i = ty; i < 32; i += 8)
    tile[i][tx] = in[(size_t)(h0 + i) * O + (o0 + tx)];
  __syncthreads();
  #pragma unroll
  for (int i = ty; i < 32; i += 8)
    out[(size_t)(o0 + i) * H + (h0 + tx)] = f32_bf16_rne(tile[tx][i]);
}

#define GLOAD(gp, lp)                                                   \
  __builtin_amdgcn_global_load_lds(                                     \
      (const __attribute__((address_space(1))) void*)(gp),              \
      (__attribute__((address_space(3))) void*)(lp), 16, 0, 0)

#define MFMA16 __builtin_amdgcn_mfma_f32_16x16x32_bf16

// =========== 128x256 4-wave GEMM, per-wave 128x64 (m201 wave shape) ==========
// C[m,n] = relu(scale * sum_k A[m,k]*B[n,k]) -> bf16.   A: MxK, B: NxK bf16.
// 4 waves 1M x 4N, per-wave 128x64 = 8x4 16x16 frags: 24 ds_read_b128 per
// 64 MFMA per K-tile-64 (22.9 reads/MFLOP, m201's ratio; was 30.5).
// 1 wave/SIMD: all hiding via ILP — reg-dbuf frags, 3-slot LDS (2-body load
// flight, counted vmcnt(12)), gloads issued AFTER the barrier (slot (t+3)%3
// = t%3 is WAR-free only once all waves' frag reads of tile t have been
// lgkm(0)'d before this barrier), T19 SGB interleave {MFMA8, DS3, VMEM2}.

__device__ __forceinline__ void read_frags24(bf16x8 (&fa)[2][8], bf16x8 (&fb)[2][4],
                                             const __bf16* sa, const __bf16* sb,
                                             int l16, int bBase, int cc0, int cc1) {
  #pragma unroll
  for (int kk = 0; kk < 2; ++kk) {
    const int c = kk ? cc1 : cc0;
    #pragma unroll
    for (int m = 0; m < 8; ++m)
      fa[kk][m] = *(const bf16x8*)(sa + (m * 16 + l16) * 64 + c);
    #pragma unroll
    for (int n = 0; n < 4; ++n)
      fb[kk][n] = *(const bf16x8*)(sb + bBase + n * 1024 + c);
  }
}

__device__ __forceinline__ void mfma64(f32x4 (&acc)[8][4],
                                       const bf16x8 (&fa)[2][8],
                                       const bf16x8 (&fb)[2][4]) {
  #pragma unroll
  for (int kk = 0; kk < 2; ++kk)
    #pragma unroll
    for (int m = 0; m < 8; ++m)
      #pragma unroll
      for (int n = 0; n < 4; ++n)
        acc[m][n] = MFMA16(fa[kk][m], fb[kk][n], acc[m][n], 0, 0, 0);
}

#define STAGE12(KO, DA, DB)                                               \
  do {                                                                    \
    GLOAD(gA0 + (KO), (DA) + 0 * 2048 + tid * 8);                         \
    GLOAD(gA1 + (KO), (DA) + 1 * 2048 + tid * 8);                         \
    GLOAD(gA2 + (KO), (DA) + 2 * 2048 + tid * 8);                         \
    GLOAD(gA3 + (KO), (DA) + 3 * 2048 + tid * 8);                         \
    GLOAD(gB0 + (KO), (DB) + 0 * 2048 + tid * 8);                         \
    GLOAD(gB1 + (KO), (DB) + 1 * 2048 + tid * 8);                         \
    GLOAD(gB2 + (KO), (DB) + 2 * 2048 + tid * 8);                         \
    GLOAD(gB3 + (KO), (DB) + 3 * 2048 + tid * 8);                         \
    GLOAD(gB4 + (KO), (DB) + 4 * 2048 + tid * 8);                         \
    GLOAD(gB5 + (KO), (DB) + 5 * 2048 + tid * 8);                         \
    GLOAD(gB6 + (KO), (DB) + 6 * 2048 + tid * 8);                         \
    GLOAD(gB7 + (KO), (DB) + 7 * 2048 + tid * 8);                         \
  } while (0)

#define SGB_INTERLEAVE                                                    \
  do {                                                                    \
    _Pragma("unroll")                                                     \
    for (int g_ = 0; g_ < 8; ++g_) {                                      \
      __builtin_amdgcn_sched_group_barrier(0x008, 8, 0);  /* 8 MFMA  */   \
      __builtin_amdgcn_sched_group_barrier(0x100, 3, 0);  /* 3 DS_RD */   \
      if (g_ < 6)                                                         \
        __builtin_amdgcn_sched_group_barrier(0x010, 2, 0); /* 2 VMEM */   \
    }                                                                     \
  } while (0)

// Regular body: t+3 < NT (stages), t+2 < NT (vmcnt 12), t+1 < NT (reads).
#define BODY_R(T, FAC, FBC, FAN, FBN)                                     \
  do {                                                                    \
    asm volatile("s_waitcnt vmcnt(12)" ::: "memory");                     \
    asm volatile("s_waitcnt lgkmcnt(0)" ::: "memory");                    \
    __builtin_amdgcn_s_barrier();                                         \
    __builtin_amdgcn_sched_barrier(0);                                    \
    {                                                                     \
      const size_t ko = (size_t)((T) + 3) * 64;                           \
      __bf16* dA = As + sst * 8192;                                       \
      __bf16* dB = Bs + sst * 16384;                                      \
      STAGE12(ko, dA, dB);                                                \
      read_frags24(FAN, FBN, As + srd * 8192, Bs + srd * 16384,           \
                   l16, bBase, cc0, cc1);                                 \
      __builtin_amdgcn_s_setprio(1);                                      \
      mfma64(acc, FAC, FBC);                                              \
      __builtin_amdgcn_s_setprio(0);                                      \
      SGB_INTERLEAVE;                                                     \
      __builtin_amdgcn_sched_barrier(0);                                  \
    }                                                                     \
    sst = sst + 1 == 3 ? 0 : sst + 1;                                     \
    srd = srd + 1 == 3 ? 0 : srd + 1;                                     \
  } while (0)

__global__ __launch_bounds__(256, 1)
void gemm128x256w(const unsigned short* __restrict__ A,
                  const unsigned short* __restrict__ B,
                  unsigned short* __restrict__ Cp, int N, int K, float scale) {
  __shared__ __bf16 As[3 * 128 * 64] __attribute__((aligned(16)));  // 48 KiB
  __shared__ __bf16 Bs[3 * 256 * 64] __attribute__((aligned(16)));  // 96 KiB

  const int tid  = threadIdx.x;
  const int lane = tid & 63;
  const int wave = tid >> 6;      // 0..3 = N-position
  const int l16  = lane & 15;
  const int kgrp = lane >> 4;     // 0..3

  const int brow0 = blockIdx.y * 128;
  const int bcol0 = blockIdx.x * 256;   // gridDim.x = 8 = #XCDs

  // ds_read addressing (swizzled): elem = row*64 + (col ^ ((row&7)<<3))
  const int xorv  = (l16 & 7) << 3;
  const int cc0   = (kgrp * 8) ^ xorv;
  const int cc1   = (32 + kgrp * 8) ^ xorv;
  const int bBase = (wave * 64 + l16) * 64;

  // staging: g-block = 32 rows x 64 elems (4 KB); 256 thr x 16 B covers it.
  const int srow = tid >> 3;                              // 0..31
  const int scol = ((tid & 7) * 8) ^ ((srow & 7) << 3);   // pre-swizzled col
  const unsigned short* gA0 = A + (size_t)(brow0 +   0 + srow) * K + scol;
  const unsigned short* gA1 = A + (size_t)(brow0 +  32 + srow) * K + scol;
  const unsigned short* gA2 = A + (size_t)(brow0 +  64 + srow) * K + scol;
  const unsigned short* gA3 = A + (size_t)(brow0 +  96 + srow) * K + scol;
  const unsigned short* gB0 = B + (size_t)(bcol0 +   0 + srow) * K + scol;
  const unsigned short* gB1 = B + (size_t)(bcol0 +  32 + srow) * K + scol;
  const unsigned short* gB2 = B + (size_t)(bcol0 +  64 + srow) * K + scol;
  const unsigned short* gB3 = B + (size_t)(bcol0 +  96 + srow) * K + scol;
  const unsigned short* gB4 = B + (size_t)(bcol0 + 128 + srow) * K + scol;
  const unsigned short* gB5 = B + (size_t)(bcol0 + 160 + srow) * K + scol;
  const unsigned short* gB6 = B + (size_t)(bcol0 + 192 + srow) * K + scol;
  const unsigned short* gB7 = B + (size_t)(bcol0 + 224 + srow) * K + scol;

  f32x4  acc[8][4] = {};
  bf16x8 fa0[2][8], fb0[2][4], fa1[2][8], fb1[2][4];

  const int NT = K >> 6;  // 32 for K=2048; code assumes NT >= 4, NT even

  // prologue: stage tiles 0,1,2 into slots 0,1,2; wait tile0; read its frags
  {
    STAGE12((size_t)0,   As + 0 * 8192, Bs + 0 * 16384);
    STAGE12((size_t)64,  As + 1 * 8192, Bs + 1 * 16384);
    STAGE12((size_t)128, As + 2 * 8192, Bs + 2 * 16384);
    asm volatile("s_waitcnt vmcnt(24)" ::: "memory");
    __builtin_amdgcn_s_barrier();
    read_frags24(fa0, fb0, As, Bs, l16, bBase, cc0, cc1);
  }

  int sst = 0, srd = 1;  // body t: stage tile t+3 -> slot t%3, read t+1 frags
  for (int t = 0; t < NT - 4; t += 2) {
    BODY_R(t,     fa0, fb0, fa1, fb1);
    BODY_R(t + 1, fa1, fb1, fa0, fb0);
  }
  BODY_R(NT - 4, fa0, fb0, fa1, fb1);   // t=NT-4: still stages tile NT-1

  // ---- tail t = NT-3: no stage; vmcnt(12) (tile NT-2 ready, NT-1 in flight)
  {
    asm volatile("s_waitcnt vmcnt(12)" ::: "memory");
    asm volatile("s_waitcnt lgkmcnt(0)" ::: "memory");
    __builtin_amdgcn_s_barrier();
    __builtin_amdgcn_sched_barrier(0);
    read_frags24(fa0, fb0, As + srd * 8192, Bs + srd * 16384,
                 l16, bBase, cc0, cc1);
    __builtin_amdgcn_s_setprio(1);
    mfma64(acc, fa1, fb1);
    __builtin_amdgcn_s_setprio(0);
    __builtin_amdgcn_sched_barrier(0);
    srd = srd + 1 == 3 ? 0 : srd + 1;
  }
  // ---- tail t = NT-2: no stage; vmcnt(0) (tile NT-1 must be ready)
  {
    asm volatile("s_waitcnt vmcnt(0)" ::: "memory");
    asm volatile("s_waitcnt lgkmcnt(0)" ::: "memory");
    __builtin_amdgcn_s_barrier();
    __builtin_amdgcn_sched_barrier(0);
    read_frags24(fa1, fb1, As + srd * 8192, Bs + srd * 16384,
                 l16, bBase, cc0, cc1);
    __builtin_amdgcn_s_setprio(1);
    mfma64(acc, fa0, fb0);
    __builtin_amdgcn_s_setprio(0);
    __builtin_amdgcn_sched_barrier(0);
  }
  // ---- tail t = NT-1: pure MFMA on last frags
  {
    asm volatile("s_waitcnt lgkmcnt(0)" ::: "memory");
    __builtin_amdgcn_s_setprio(1);
    mfma64(acc, fa1, fb1);
    __builtin_amdgcn_s_setprio(0);
  }

  // epilogue: relu(acc*scale) -> bf16. D: col=lane&15, row=(lane>>4)*4+j
  const int crow0 = brow0 + kgrp * 4;
  const int ccol0 = bcol0 + wave * 64 + l16;
  #pragma unroll
  for (int m = 0; m < 8; ++m)
    #pragma unroll
    for (int n = 0; n < 4; ++n)
      #pragma unroll
      for (int j = 0; j < 4; ++j) {
        float v = acc[m][n][j] * scale;
        v = v > 0.0f ? v : 0.0f;
        Cp[(size_t)(crow0 + m * 16 + j) * N + (ccol0 + n * 16)] = f32_bf16_rne(v);
      }
}

// ---------------- 128x128 m97-structure GEMM (readout only) ------------------
__global__ __launch_bounds__(256)
void gemm_bt_f32(const unsigned short* __restrict__ A,
                 const unsigned short* __restrict__ B,
                 float* __restrict__ C, int N, int K, float scale) {
  __shared__ __bf16 As[128 * 32] __attribute__((aligned(16)));
  __shared__ __bf16 Bs[128 * 32] __attribute__((aligned(16)));

  const int tid  = threadIdx.x;
  const int lane = tid & 63;
  const int wave = tid >> 6;
  const int wr   = wave >> 1, wc = wave & 1;
  const int l16  = lane & 15, kgrp = lane >> 4;

  const int brow0 = blockIdx.y * 128;
  const int bcol0 = blockIdx.x * 128;

  const int offb  = wave * 2048 + lane * 16;
  const int srow  = offb >> 6;
  const int selem = (offb & 63) >> 1;
  const unsigned short* gA0 = A + (size_t)(brow0 + srow) * K + selem;
  const unsigned short* gA1 = A + (size_t)(brow0 + srow + 16) * K + selem;
  const unsigned short* gB0 = B + (size_t)(bcol0 + srow) * K + selem;
  const unsigned short* gB1 = B + (size_t)(bcol0 + srow + 16) * K + selem;
  __bf16* lA0 = &As[wave * 1024];
  __bf16* lA1 = &As[wave * 1024 + 512];
  __bf16* lB0 = &Bs[wave * 1024];
  __bf16* lB1 = &Bs[wave * 1024 + 512];

  f32x4 acc[4][4] = {};
  const int aoff = (wr * 64 + l16) * 32 + kgrp * 8;
  const int boff = (wc * 64 + l16) * 32 + kgrp * 8;

  for (int k0 = 0; k0 < K; k0 += 32) {
    GLOAD(gA0 + k0, lA0);
    GLOAD(gA1 + k0, lA1);
    GLOAD(gB0 + k0, lB0);
    GLOAD(gB1 + k0, lB1);
    asm volatile("s_waitcnt vmcnt(0)" ::: "memory");
    __syncthreads();

    bf16x8 af[4], bfv[4];
    #pragma unroll
    for (int m = 0; m < 4; ++m)
      af[m] = *(const bf16x8*)(As + aoff + m * 16 * 32);
    #pragma unroll
    for (int n = 0; n < 4; ++n)
      bfv[n] = *(const bf16x8*)(Bs + boff + n * 16 * 32);
    #pragma unroll
    for (int m = 0; m < 4; ++m)
      #pragma unroll
      for (int n = 0; n < 4; ++n)
        acc[m][n] = MFMA16(af[m], bfv[n], acc[m][n], 0, 0, 0);
    __syncthreads();
  }

  const int crow0 = brow0 + wr * 64 + kgrp * 4;
  const int ccol0 = bcol0 + wc * 64 + l16;
  #pragma unroll
  for (int m = 0; m < 4; ++m)
    #pragma unroll
    for (int n = 0; n < 4; ++n)
      #pragma unroll
      for (int j = 0; j < 4; ++j)
        C[(size_t)(crow0 + m * 16 + j) * N + (ccol0 + n * 16)] =
            acc[m][n][j] * scale;
}

extern "C" void kernel_launch(void* const* d_in, const int* in_sizes, int n_in,
                              void* d_out, int out_size, void* d_ws, size_t ws_size,
                              hipStream_t stream) {
  const float* x    = (const float*)d_in[0];  // (4096, 2048)
  const float* W    = (const float*)d_in[1];  // (8, 2048, 2048)
  const float* beta = (const float*)d_in[2];  // (2048, 1024)
  float* out = (float*)d_out;                 // (4096, 1024) f32

  const int Bn = 4096, H = 2048, L = 8, O = 1024;

  // ws layout (bf16 as ushort): y0 | y1 | Wb[8 layers] | betaT  = 105 MB
  unsigned short* y0    = (unsigned short*)d_ws;
  unsigned short* y1    = y0 + (size_t)Bn * H;
  unsigned short* Wb    = y1 + (size_t)Bn * H;
  unsigned short* betaT = Wb + (size_t)L * H * H;

  // all 8 W layers -> bf16 in ONE kernel
  {
    int n8 = L * H * H / 8;
    cvt_f32_bf16<<<2048, 256, 0, stream>>>(W, Wb, n8);
  }
  // x -> bf16
  {
    int n8 = Bn * H / 8;
    int grid = (n8 + 255) / 256;
    if (grid > 2048) grid = 2048;
    cvt_f32_bf16<<<grid, 256, 0, stream>>>(x, y0, n8);
  }
  cvt_transpose<<<dim3(O / 32, H / 32), 256, 0, stream>>>(beta, betaT, H, O);

  const float s1 = 0.02209708691207961f;  // 1/sqrt(2048)
  unsigned short* yin = y0;
  unsigned short* yout = y1;
  for (int l = 0; l < L; ++l) {
    gemm128x256w<<<dim3(H / 256, Bn / 128), 256, 0, stream>>>(
        yin, Wb + (size_t)l * H * H, yout, H, H, s1);
    unsigned short* t = yin; yin = yout; yout = t;
  }
  gemm_bt_f32<<<dim3(O / 128, Bn / 128), 256, 0, stream>>>(yin, betaT, out, O, H,
                                                           1.0f / 2048.0f);
}